// Round 7
// baseline (4985.800 us; speedup 1.0000x reference)
//
#include <hip/hip_runtime.h>
#include <hip/hip_bf16.h>

#define Bb 32
#define Ss 1024
#define Vv 32000
#define Ee 512
#define Hh 512
#define Ww 128
#define GXC 3072              // 2 dirs * 3H gate columns
#define MR  (Bb * Ss)         // 32768 GEMM rows

typedef short short8  __attribute__((ext_vector_type(8)));
typedef float floatx4 __attribute__((ext_vector_type(4)));
typedef _Float16 f16x2 __attribute__((ext_vector_type(2)));
typedef _Float16 f16x8 __attribute__((ext_vector_type(8)));
typedef unsigned long long u64;

__device__ inline unsigned short bf16bits(float x) {
  return __builtin_bit_cast(unsigned short, __float2bfloat16(x));
}
__device__ inline unsigned f16w(float x) {
  return (unsigned)__builtin_bit_cast(unsigned short, (_Float16)x);
}

template<typename T> __device__ inline T gxstore(float v);
template<> __device__ inline float gxstore<float>(float v) { return v; }
template<> __device__ inline __hip_bfloat16 gxstore<__hip_bfloat16>(float v) { return __float2bfloat16(v); }
template<typename T> __device__ inline float gxload(T v);
template<> __device__ inline float gxload<float>(float v) { return v; }
template<> __device__ inline float gxload<__hip_bfloat16>(__hip_bfloat16 v) { return __bfloat162float(v); }

// ---------------- prep kernels ----------------

__global__ void prep_emb(const float* __restrict__ emb, unsigned short* __restrict__ out) {
  int i = (blockIdx.x * 256 + threadIdx.x) * 4;
  float4 v = *reinterpret_cast<const float4*>(emb + i);
  bool z = (i < Ee);                               // first row = token 0 (padding_idx)
  ushort4 o;
  o.x = z ? (unsigned short)0 : bf16bits(v.x);
  o.y = z ? (unsigned short)0 : bf16bits(v.y);
  o.z = z ? (unsigned short)0 : bf16bits(v.z);
  o.w = z ? (unsigned short)0 : bf16bits(v.w);
  *reinterpret_cast<ushort4*>(out + i) = o;
}

__global__ void prep_wih(const float* __restrict__ wf, const float* __restrict__ wb,
                         unsigned short* __restrict__ out) {
  int i = (blockIdx.x * 256 + threadIdx.x) * 4;   // over 3072*512
  const float* src = (i < 1536 * 512) ? (wf + i) : (wb + (i - 1536 * 512));
  float4 v = *reinterpret_cast<const float4*>(src);
  ushort4 o;
  o.x = bf16bits(v.x); o.y = bf16bits(v.y); o.z = bf16bits(v.z); o.w = bf16bits(v.w);
  *reinterpret_cast<ushort4*>(out + i) = o;
}

// W_hh -> f16 B-fragments for 16x16x32 MFMA.
//   uint4 frag: out_u4[ (((dir*32 + jblk)*3 + g)*16 + kt)*64 + lane ]
//   element e (0..7): W_dir[g*512 + jblk*16 + (lane&15)][kt*32 + (lane>>4)*8 + e]
//   dword d holds elements 2d, 2d+1.
__global__ void prep_whh(const float* __restrict__ wf, const float* __restrict__ wb,
                         unsigned* __restrict__ out) {
  int o = blockIdx.x * 256 + threadIdx.x;  // < 786432 dwords
  int d    = o & 3;
  int u4   = o >> 2;
  int lane = u4 & 63;
  int kt   = (u4 >> 6) & 15;
  int rest = u4 >> 10;                     // (dir*32+jblk)*3 + g, < 192
  int g    = rest % 3;
  int dj   = rest / 3;
  int jblk = dj & 31;
  int dir  = dj >> 5;
  int row  = g * 512 + jblk * 16 + (lane & 15);
  int k    = kt * 32 + ((lane >> 4) << 3) + 2 * d;
  const float* W = dir ? wb : wf;
  out[o] = f16w(W[(size_t)row * Hh + k]) | (f16w(W[(size_t)row * Hh + k + 1]) << 16);
}

__global__ void zero_hx(unsigned* __restrict__ hxw) {
  hxw[blockIdx.x * 256 + threadIdx.x] = 0u;   // <<<256,256>>> : 65536 words = 32768 u64
}

// ---------------- input-gate GEMM ----------------
template<typename GXT>
__global__ __launch_bounds__(256)
void gx_gemm(const int* __restrict__ seq, const unsigned short* __restrict__ embb,
             const unsigned short* __restrict__ wihb, GXT* __restrict__ gx) {
  __shared__ short As[128][80];
  __shared__ short Bs[128][80];
  __shared__ int toks[128];
  const int tid = threadIdx.x;
  const int m0 = blockIdx.y * 128;
  const int n0 = blockIdx.x * 128;
  if (tid < 128) {
    int r = m0 + tid;                       // row = s*32 + b
    toks[tid] = seq[(r & 31) * Ss + (r >> 5)];
  }
  __syncthreads();
  const int lane = tid & 63, wave = tid >> 6;
  const int wm = (wave >> 1) * 64, wn = (wave & 1) * 64;
  floatx4 zero = {0.f, 0.f, 0.f, 0.f};
  floatx4 acc[4][4];
  #pragma unroll
  for (int a = 0; a < 4; ++a)
    #pragma unroll
    for (int c = 0; c < 4; ++c) acc[a][c] = zero;

  for (int k0 = 0; k0 < Ee; k0 += 64) {
    #pragma unroll
    for (int i = 0; i < 4; ++i) {
      int slot = i * 256 + tid;
      int row = slot >> 3, cq = (slot & 7) * 8;
      uint4 va = *reinterpret_cast<const uint4*>(embb + (size_t)toks[row] * Ee + k0 + cq);
      *reinterpret_cast<uint4*>(&As[row][cq]) = va;
      uint4 vb = *reinterpret_cast<const uint4*>(wihb + (size_t)(n0 + row) * Ee + k0 + cq);
      *reinterpret_cast<uint4*>(&Bs[row][cq]) = vb;
    }
    __syncthreads();
    #pragma unroll
    for (int ks = 0; ks < 2; ++ks) {
      short8 af[4], bfr[4];
      #pragma unroll
      for (int mi = 0; mi < 4; ++mi)
        af[mi] = *reinterpret_cast<const short8*>(&As[wm + mi * 16 + (lane & 15)][ks * 32 + (lane >> 4) * 8]);
      #pragma unroll
      for (int ni = 0; ni < 4; ++ni)
        bfr[ni] = *reinterpret_cast<const short8*>(&Bs[wn + ni * 16 + (lane & 15)][ks * 32 + (lane >> 4) * 8]);
      #pragma unroll
      for (int mi = 0; mi < 4; ++mi)
        #pragma unroll
        for (int ni = 0; ni < 4; ++ni)
          acc[mi][ni] = __builtin_amdgcn_mfma_f32_16x16x32_bf16(af[mi], bfr[ni], acc[mi][ni], 0, 0, 0);
    }
    __syncthreads();
  }
  #pragma unroll
  for (int mi = 0; mi < 4; ++mi) {
    #pragma unroll
    for (int ni = 0; ni < 4; ++ni) {
      int r0 = m0 + wm + mi * 16 + ((lane >> 4) * 4);
      int c  = n0 + wn + ni * 16 + (lane & 15);
      #pragma unroll
      for (int j = 0; j < 4; ++j)
        gx[(size_t)(r0 + j) * GXC + c] = gxstore<GXT>(acc[mi][ni][j]);
    }
  }
}

// ---------------- recurrence: batched MFMA, 4 groups x 32 blocks ------------
// Group = (dir, bhalf of 16). Block owns 16 h-cols x 3 gates; per step:
// gh[16b, 48c] = h[16,512] @ W^T via 3 gate-waves x 16 mfma_16x16x32_f16
// (B-frags: 64 VGPRs, loop-invariant). h in LDS f16, XOR-swizzled
// (^((b&7)<<4), T2). Epilogue in-block; exchange = R6's proven fence-free
// tagged words (u64 = 2x{tag16|f16}, relaxed agent atomics, 2-parity,
// skew<=1 induction). Wave 3 prefetches next step's gx during MFMA.

#define H16(M) M(0) M(1) M(2) M(3) M(4) M(5) M(6) M(7) \
               M(8) M(9) M(10) M(11) M(12) M(13) M(14) M(15)

#define BDECL(i) uint4 B_##i;
#define BLOAD(i) B_##i = wq[(i) * 64];
#define BPIN(i) asm volatile("" : "+v"(B_##i.x), "+v"(B_##i.y), "+v"(B_##i.z), "+v"(B_##i.w));
#define MST(i) { \
  short8 ar = *reinterpret_cast<const short8*>(hb + hsel + (habase ^ ((i) << 6))); \
  acc = __builtin_amdgcn_mfma_f32_16x16x32_f16( \
        __builtin_bit_cast(f16x8, ar), __builtin_bit_cast(f16x8, B_##i), acc, 0, 0, 0); }

#define GDECL(r) u64 gv_##r = 0;
#define GLOAD(r) { int u = tid + ((r) << 8); \
  if (u < 3968) { int sb = u >> 7; sb += (sb >= jblk); \
    gv_##r = __hip_atomic_load(hxg + (size_t)sb * 128 + (u & 127), \
                               __ATOMIC_RELAXED, __HIP_MEMORY_SCOPE_AGENT); } }
#define GPOLL(r) { int u = tid + ((r) << 8); \
  if (u < 3968) { int sb = u >> 7; sb += (sb >= jblk); int ww = u & 127; \
    const u64* ap = hxg + (size_t)sb * 128 + ww; \
    while ((((unsigned)gv_##r & 0xffffu) != want) | \
           (((unsigned)(gv_##r >> 32) & 0xffffu) != want)) \
      gv_##r = __hip_atomic_load(ap, __ATOMIC_RELAXED, __HIP_MEMORY_SCOPE_AGENT); \
    unsigned pk = (((unsigned)(gv_##r >> 16)) & 0xffffu) | ((unsigned)(gv_##r >> 48) << 16); \
    int bb = ww >> 3, cc = sb * 16 + 2 * (ww & 7); \
    *reinterpret_cast<unsigned*>(hb + hsel + ((((bb) << 10) + (cc << 1)) ^ ((bb & 7) << 4))) = pk; } }

template<typename GXT>
__global__ __launch_bounds__(256, 1)
void rnn_kernel(const GXT* __restrict__ gx, const unsigned* __restrict__ whh2,
                const float* __restrict__ bih_f, const float* __restrict__ bhh_f,
                const float* __restrict__ bih_b, const float* __restrict__ bhh_b,
                const int* __restrict__ layout, float* __restrict__ out,
                u64* __restrict__ hx) {
  __shared__ char  hbs[2 * 16 * 512 * 2];    // h f16, 2 parities, swizzled
  __shared__ float gxb[2][3][16][17];        // gx staging, 2 parities
  __shared__ float sbuf[3][16][17];          // gate pre-activations
  __shared__ int   lay_l[16 * 129];

  const int tid  = threadIdx.x;
  const int w    = tid >> 6;
  const int lane = tid & 63;
  const int grp  = blockIdx.x >> 5;          // dir*2 + bhalf
  const int jblk = blockIdx.x & 31;
  const int dir  = grp >> 1;
  const int bh   = grp & 1;
  char* hb = hbs;

  // B-fragments (loop-invariant; wave 3 loads gate 0 harmlessly)
  const uint4* wq = reinterpret_cast<const uint4*>(whh2)
                    + (size_t)(((dir * 32 + jblk) * 3 + (w < 3 ? w : 0)) * 16) * 64 + lane;
  H16(BDECL)
  H16(BLOAD)

  // init LDS
  for (int v = tid; v < 8192; v += 256) reinterpret_cast<unsigned*>(hbs)[v] = 0u;
  for (int v = tid; v < 16 * 129; v += 256)
    lay_l[v] = layout[(bh * 16 + v / 129) * (Ww + 1) + v % 129];

  const int t0 = dir ? (Ss - 1) : 0;
  const int tstep = dir ? -1 : 1;

  // prologue: gxb[0] <- gx[t0]
  for (int v = tid; v < 768; v += 256) {
    int g = v >> 8, bb = (v >> 4) & 15, cc = v & 15;
    gxb[0][g][bb][cc] = gxload<GXT>(gx[((size_t)t0 * Bb + bh * 16 + bb) * GXC
                                        + dir * 1536 + g * 512 + jblk * 16 + cc]);
  }

  // combiner per-thread state (tid < 128): b = tid>>3, cols 2*(tid&7), +1
  const int eb  = tid >> 3;
  const int ec0 = 2 * (tid & 7);
  const int cg0 = jblk * 16 + ec0;
  const int bg  = bh * 16 + eb;
  float biA0 = 0, biA1 = 0, biA2 = 0, bhA0 = 0, bhA1 = 0, bhA2 = 0;
  float biB0 = 0, biB1 = 0, biB2 = 0, bhB0 = 0, bhB1 = 0, bhB2 = 0;
  if (tid < 128) {
    const float* bi = dir ? bih_b : bih_f;
    const float* bv = dir ? bhh_b : bhh_f;
    biA0 = bi[cg0];        biA1 = bi[512 + cg0];  biA2 = bi[1024 + cg0];
    bhA0 = bv[cg0];        bhA1 = bv[512 + cg0];  bhA2 = bv[1024 + cg0];
    biB0 = bi[cg0 + 1];    biB1 = bi[513 + cg0];  biB2 = bi[1025 + cg0];
    bhB0 = bv[cg0 + 1];    bhB1 = bv[513 + cg0];  bhB2 = bv[1025 + cg0];
  }
  __syncthreads();

  float h0f = 0.f, h1f = 0.f, mx0 = -3.0e38f, mx1 = -3.0e38f;
  int seg = dir ? (Ww - 1) : 0;
  int t = t0, p = 0;

  #pragma unroll 1
  for (int it = 0; it < Ss; ++it, t += tstep) {
    const int P = p ^ 1;
    const int hsel = p * 16384;
    // ---- phase G: gather sibling h_it into hbuf[p] ----
    if (it > 0) {
      const unsigned want = (unsigned)it;
      const u64* hxg = hx + (size_t)(p * 4 + grp) * 32 * 128;
      H16(GDECL)
      H16(GLOAD)
      H16(GPOLL)
    }
    __syncthreads();
    // ---- phase M: MFMA (waves 0-2) / gx prefetch (wave 3) ----
    if (w < 3) {
      floatx4 acc = {0.f, 0.f, 0.f, 0.f};
      const int ab = lane & 15;
      const int habase = (ab << 10) | (((lane >> 4) << 4) ^ ((ab & 7) << 4));
      H16(MST)
      H16(BPIN)
      int ccol = lane & 15, crow = (lane >> 4) << 2;
      #pragma unroll
      for (int jj = 0; jj < 4; ++jj) sbuf[w][crow + jj][ccol] = acc[jj];
    } else if (it + 1 < Ss) {
      int tn = t + tstep;
      #pragma unroll
      for (int r = 0; r < 12; ++r) {
        int v = r * 64 + lane;
        int g = v >> 8, bb = (v >> 4) & 15, cc = v & 15;
        gxb[P][g][bb][cc] = gxload<GXT>(gx[((size_t)tn * Bb + bh * 16 + bb) * GXC
                                            + dir * 1536 + g * 512 + jblk * 16 + cc]);
      }
    }
    __syncthreads();
    // ---- phase E: combine gates, update h, publish ----
    if (tid < 128) {
      float s0a = sbuf[0][eb][ec0],     s1a = sbuf[1][eb][ec0],     s2a = sbuf[2][eb][ec0];
      float s0b = sbuf[0][eb][ec0 + 1], s1b = sbuf[1][eb][ec0 + 1], s2b = sbuf[2][eb][ec0 + 1];
      float ga0 = gxb[p][0][eb][ec0],     ga1 = gxb[p][1][eb][ec0],     ga2 = gxb[p][2][eb][ec0];
      float gb0 = gxb[p][0][eb][ec0 + 1], gb1 = gxb[p][1][eb][ec0 + 1], gb2 = gxb[p][2][eb][ec0 + 1];
      {
        float rs = ga0 + biA0 + bhA0 + s0a;
        float zs = ga1 + biA1 + bhA1 + s1a;
        float nh = bhA2 + s2a;
        float r = 1.f / (1.f + __expf(-rs));
        float z = 1.f / (1.f + __expf(-zs));
        float x = ga2 + biA2 + r * nh;
        x = fminf(fmaxf(x, -15.f), 15.f);
        float e = __expf(2.f * x);
        float n = (e - 1.f) / (e + 1.f);
        h0f = (1.f - z) * n + z * h0f;
      }
      {
        float rs = gb0 + biB0 + bhB0 + s0b;
        float zs = gb1 + biB1 + bhB1 + s1b;
        float nh = bhB2 + s2b;
        float r = 1.f / (1.f + __expf(-rs));
        float z = 1.f / (1.f + __expf(-zs));
        float x = gb2 + biB2 + r * nh;
        x = fminf(fmaxf(x, -15.f), 15.f);
        float e = __expf(2.f * x);
        float n = (e - 1.f) / (e + 1.f);
        h1f = (1.f - z) * n + z * h1f;
      }
      unsigned hf0 = f16w(h0f), hf1 = f16w(h1f);
      unsigned tagv = (unsigned)(it + 1);
      u64 pv = (u64)(tagv | (hf0 << 16)) | ((u64)(tagv | (hf1 << 16)) << 32);
      __hip_atomic_store(hx + ((size_t)(P * 4 + grp) * 32 + jblk) * 128 + tid, pv,
                         __ATOMIC_RELAXED, __HIP_MEMORY_SCOPE_AGENT);
      *reinterpret_cast<unsigned*>(hb + P * 16384
          + (((eb << 10) + (cg0 << 1)) ^ ((eb & 7) << 4))) = hf0 | (hf1 << 16);
      mx0 = fmaxf(mx0, h0f);
      mx1 = fmaxf(mx1, h1f);
      bool fl = dir ? (t == lay_l[eb * 129 + seg]) : (t + 1 == lay_l[eb * 129 + seg + 1]);
      if (fl) {
        size_t ob = ((size_t)bg * Ww + seg) * 1024 + dir * 512 + cg0;
        out[ob] = mx0; out[ob + 1] = mx1;
        mx0 = -3.0e38f; mx1 = -3.0e38f;
        seg += tstep;
      }
    }
    p = P;
  }
  if (tid < 128) {                           // final hidden [2][B][H]
    size_t fb = (size_t)Bb * Ww * 1024 + (size_t)dir * (Bb * Hh) + (size_t)bg * Hh + cg0;
    out[fb] = h0f; out[fb + 1] = h1f;
  }
}

// ---------------- host launcher ----------------
extern "C" void kernel_launch(void* const* d_in, const int* in_sizes, int n_in,
                              void* d_out, int out_size, void* d_ws, size_t ws_size,
                              hipStream_t stream) {
  const int*   seq    = (const int*)  d_in[0];
  const int*   layout = (const int*)  d_in[3];
  const float* emb    = (const float*)d_in[4];
  const float* Wih_f  = (const float*)d_in[5];
  const float* Whh_f  = (const float*)d_in[6];
  const float* bih_f  = (const float*)d_in[7];
  const float* bhh_f  = (const float*)d_in[8];
  const float* Wih_b  = (const float*)d_in[9];
  const float* Whh_b  = (const float*)d_in[10];
  const float* bih_b  = (const float*)d_in[11];
  const float* bhh_b  = (const float*)d_in[12];
  float* out = (float*)d_out;

  char* ws = (char*)d_ws;
  unsigned short* embb  = (unsigned short*)ws;                      // 32,768,000 B
  unsigned short* wihb  = (unsigned short*)(ws + 32768000);         //  3,145,728 B
  unsigned*       whh2  = (unsigned*)      (ws + 35913728);         //  3,145,728 B
  u64*            hxw   = (u64*)           (ws + 39059456);         //    262,144 B
  void*           gxp   = (void*)          (ws + 39321600);

  const size_t need_f32 = 39321600ULL + (size_t)MR * GXC * 4;       // ~442.0 MB
  const size_t need_b16 = 39321600ULL + (size_t)MR * GXC * 2;       // ~240.6 MB
  if (ws_size < need_b16) return;

  prep_emb<<<(Vv * Ee) / 4 / 256, 256, 0, stream>>>(emb, embb);
  prep_wih<<<(GXC * Ee) / 4 / 256, 256, 0, stream>>>(Wih_f, Wih_b, wihb);
  prep_whh<<<786432 / 256, 256, 0, stream>>>(Whh_f, Whh_b, whh2);
  zero_hx<<<256, 256, 0, stream>>>((unsigned*)hxw);   // stream-ordered: before rnn

  if (ws_size >= need_f32) {
    gx_gemm<float><<<dim3(GXC / 128, MR / 128), 256, 0, stream>>>(seq, embb, wihb, (float*)gxp);
    rnn_kernel<float><<<128, 256, 0, stream>>>((const float*)gxp, whh2,
                                               bih_f, bhh_f, bih_b, bhh_b, layout, out, hxw);
  } else {
    gx_gemm<__hip_bfloat16><<<dim3(GXC / 128, MR / 128), 256, 0, stream>>>(seq, embb, wihb, (__hip_bfloat16*)gxp);
    rnn_kernel<__hip_bfloat16><<<128, 256, 0, stream>>>((const __hip_bfloat16*)gxp, whh2,
                                                        bih_f, bhh_f, bih_b, bhh_b, layout, out, hxw);
  }
}

// Round 9
// 2422.100 us; speedup vs baseline: 2.0585x; 2.0585x over previous
//
#include <hip/hip_runtime.h>
#include <hip/hip_bf16.h>

#define Bb 32
#define Ss 1024
#define Vv 32000
#define Ee 512
#define Hh 512
#define Ww 128
#define GXC 3072              // 2 dirs * 3H gate columns
#define MR  (Bb * Ss)         // 32768 GEMM rows

typedef short short8  __attribute__((ext_vector_type(8)));
typedef float floatx4 __attribute__((ext_vector_type(4)));
typedef _Float16 f16x2 __attribute__((ext_vector_type(2)));
typedef unsigned long long u64;

__device__ inline float dot2f(unsigned w, unsigned h, float acc) {
  return __builtin_amdgcn_fdot2(__builtin_bit_cast(f16x2, w),
                                __builtin_bit_cast(f16x2, h), acc, false);
}
__device__ inline unsigned short bf16bits(float x) {
  return __builtin_bit_cast(unsigned short, __float2bfloat16(x));
}

template<typename T> __device__ inline T gxstore(float v);
template<> __device__ inline float gxstore<float>(float v) { return v; }
template<> __device__ inline __hip_bfloat16 gxstore<__hip_bfloat16>(float v) { return __float2bfloat16(v); }
template<typename T> __device__ inline float gxload(T v);
template<> __device__ inline float gxload<float>(float v) { return v; }
template<> __device__ inline float gxload<__hip_bfloat16>(__hip_bfloat16 v) { return __bfloat162float(v); }

// ---------------- prep kernels ----------------

__global__ void prep_emb(const float* __restrict__ emb, unsigned short* __restrict__ out) {
  int i = (blockIdx.x * 256 + threadIdx.x) * 4;
  float4 v = *reinterpret_cast<const float4*>(emb + i);
  bool z = (i < Ee);                               // first row = token 0 (padding_idx)
  ushort4 o;
  o.x = z ? (unsigned short)0 : bf16bits(v.x);
  o.y = z ? (unsigned short)0 : bf16bits(v.y);
  o.z = z ? (unsigned short)0 : bf16bits(v.z);
  o.w = z ? (unsigned short)0 : bf16bits(v.w);
  *reinterpret_cast<ushort4*>(out + i) = o;
}

__global__ void prep_wih(const float* __restrict__ wf, const float* __restrict__ wb,
                         unsigned short* __restrict__ out) {
  int i = (blockIdx.x * 256 + threadIdx.x) * 4;   // over 3072*512
  const float* src = (i < 1536 * 512) ? (wf + i) : (wb + (i - 1536 * 512));
  float4 v = *reinterpret_cast<const float4*>(src);
  ushort4 o;
  o.x = bf16bits(v.x); o.y = bf16bits(v.y); o.z = bf16bits(v.z); o.w = bf16bits(v.w);
  *reinterpret_cast<ushort4*>(out + i) = o;
}

// W_hh -> f16x2 for the 4-shard rnn (512 thr/block):
//   uint4 chunk: out_u4[ ((dir*4 + j)*48 + g*16 + i)*512 + tid ]
//   word m = pack(W[row][2kp], W[row][2kp+1])
//   tid: c=tid>>2 (local hcol), q=tid&3 (K-quarter)
//   row = g*512 + j*128 + c,  kp = q*64 + i*4 + m
__global__ void prep_whh(const float* __restrict__ wf, const float* __restrict__ wb,
                         unsigned* __restrict__ out) {
  int o = blockIdx.x * 256 + threadIdx.x;  // < 786432 words
  int m    = o & 3;
  int u4   = o >> 2;
  int tid  = u4 & 511;
  int rest = u4 >> 9;
  int i    = rest & 15;
  int rest2 = rest >> 4;                   // (dir*4+j)*3 + g, < 24
  int g    = rest2 % 3;
  int rest3 = rest2 / 3;                   // dir*4 + j
  int j    = rest3 & 3;
  int dir  = rest3 >> 2;
  int c    = tid >> 2;
  int q    = tid & 3;
  int row  = g * 512 + j * 128 + c;
  int kp   = q * 64 + i * 4 + m;
  const float* W = dir ? wb : wf;
  unsigned lo = __builtin_bit_cast(unsigned short, (_Float16)W[(size_t)row * Hh + 2 * kp]);
  unsigned hi = __builtin_bit_cast(unsigned short, (_Float16)W[(size_t)row * Hh + 2 * kp + 1]);
  out[o] = lo | (hi << 16);
}

__global__ void zero_hx(unsigned* __restrict__ hxw) {
  hxw[blockIdx.x * 256 + threadIdx.x] = 0u;   // <<<256,256>>> : 65536 words
}

// ---------------- input-gate GEMM ----------------
template<typename GXT>
__global__ __launch_bounds__(256)
void gx_gemm(const int* __restrict__ seq, const unsigned short* __restrict__ embb,
             const unsigned short* __restrict__ wihb, GXT* __restrict__ gx) {
  __shared__ short As[128][80];
  __shared__ short Bs[128][80];
  __shared__ int toks[128];
  const int tid = threadIdx.x;
  const int m0 = blockIdx.y * 128;
  const int n0 = blockIdx.x * 128;
  if (tid < 128) {
    int r = m0 + tid;                       // row = s*32 + b
    toks[tid] = seq[(r & 31) * Ss + (r >> 5)];
  }
  __syncthreads();
  const int lane = tid & 63, wave = tid >> 6;
  const int wm = (wave >> 1) * 64, wn = (wave & 1) * 64;
  floatx4 zero = {0.f, 0.f, 0.f, 0.f};
  floatx4 acc[4][4];
  #pragma unroll
  for (int a = 0; a < 4; ++a)
    #pragma unroll
    for (int c = 0; c < 4; ++c) acc[a][c] = zero;

  for (int k0 = 0; k0 < Ee; k0 += 64) {
    #pragma unroll
    for (int i = 0; i < 4; ++i) {
      int slot = i * 256 + tid;
      int row = slot >> 3, cq = (slot & 7) * 8;
      uint4 va = *reinterpret_cast<const uint4*>(embb + (size_t)toks[row] * Ee + k0 + cq);
      *reinterpret_cast<uint4*>(&As[row][cq]) = va;
      uint4 vb = *reinterpret_cast<const uint4*>(wihb + (size_t)(n0 + row) * Ee + k0 + cq);
      *reinterpret_cast<uint4*>(&Bs[row][cq]) = vb;
    }
    __syncthreads();
    #pragma unroll
    for (int ks = 0; ks < 2; ++ks) {
      short8 af[4], bfr[4];
      #pragma unroll
      for (int mi = 0; mi < 4; ++mi)
        af[mi] = *reinterpret_cast<const short8*>(&As[wm + mi * 16 + (lane & 15)][ks * 32 + (lane >> 4) * 8]);
      #pragma unroll
      for (int ni = 0; ni < 4; ++ni)
        bfr[ni] = *reinterpret_cast<const short8*>(&Bs[wn + ni * 16 + (lane & 15)][ks * 32 + (lane >> 4) * 8]);
      #pragma unroll
      for (int mi = 0; mi < 4; ++mi)
        #pragma unroll
        for (int ni = 0; ni < 4; ++ni)
          acc[mi][ni] = __builtin_amdgcn_mfma_f32_16x16x32_bf16(af[mi], bfr[ni], acc[mi][ni], 0, 0, 0);
    }
    __syncthreads();
  }
  #pragma unroll
  for (int mi = 0; mi < 4; ++mi) {
    #pragma unroll
    for (int ni = 0; ni < 4; ++ni) {
      int r0 = m0 + wm + mi * 16 + ((lane >> 4) * 4);
      int c  = n0 + wn + ni * 16 + (lane & 15);
      #pragma unroll
      for (int j = 0; j < 4; ++j)
        gx[(size_t)(r0 + j) * GXC + c] = gxstore<GXT>(acc[mi][ni][j]);
    }
  }
}

// ---------------- recurrence: 4 CUs/chain, fence-free tagged exchange -------
// R6 structure (2.60 ms proven) + two risk-free edits:
//  (1) barrier A DELETED: it ordered nothing (gather writes parity P sibling
//      slots; CHUNK reads parity p; own-slot writes are ordered by barrier C).
//      Gather waves now start polling the MALL while other waves are still in
//      dots/epilogue -> poll latency overlaps compute.
//  (2) gx prefetched one full step ahead (HBM latency ~0.4us > old 0.2us
//      cover; now covered by ~2us).
// Exchange protocol byte-identical to R6: tagged word {tag16=it+1 | h_f16},
// relaxed agent-scope atomics, 2-parity buffer, no fences (R8 lesson: never
// gate correctness on placement heuristics).

#define H16(M) M(0) M(1) M(2) M(3) M(4) M(5) M(6) M(7) \
               M(8) M(9) M(10) M(11) M(12) M(13) M(14) M(15)

#define WDECL(i) uint4 W0_##i, W1_##i, W2_##i;
#define WLOAD(i) W0_##i = wq[(i) * 512]; \
                 W1_##i = wq[(16 + (i)) * 512]; \
                 W2_##i = wq[(32 + (i)) * 512];
#define WPIN(i) asm volatile("" : "+v"(W0_##i.x), "+v"(W0_##i.y), "+v"(W0_##i.z), "+v"(W0_##i.w), \
                                  "+v"(W1_##i.x), "+v"(W1_##i.y), "+v"(W1_##i.z), "+v"(W1_##i.w), \
                                  "+v"(W2_##i.x), "+v"(W2_##i.y), "+v"(W2_##i.z), "+v"(W2_##i.w));
#define CHUNK(i) { uint4 Hq = hq4[i]; \
  s0 = dot2f(W0_##i.x, Hq.x, s0); s0 = dot2f(W0_##i.y, Hq.y, s0); \
  s0 = dot2f(W0_##i.z, Hq.z, s0); s0 = dot2f(W0_##i.w, Hq.w, s0); \
  s1 = dot2f(W1_##i.x, Hq.x, s1); s1 = dot2f(W1_##i.y, Hq.y, s1); \
  s1 = dot2f(W1_##i.z, Hq.z, s1); s1 = dot2f(W1_##i.w, Hq.w, s1); \
  s2 = dot2f(W2_##i.x, Hq.x, s2); s2 = dot2f(W2_##i.y, Hq.y, s2); \
  s2 = dot2f(W2_##i.z, Hq.z, s2); s2 = dot2f(W2_##i.w, Hq.w, s2); }

#define TAGOK(a, b2, want) \
  (((((unsigned)((a)  >> 16)) & 0xffffu) == (want)) & \
   ((((unsigned)((a)  >> 48))) == (want)) & \
   ((((unsigned)((b2) >> 16)) & 0xffffu) == (want)) & \
   ((((unsigned)((b2) >> 48))) == (want)))

template<typename GXT>
__global__ __launch_bounds__(512, 2)
void rnn_kernel(const GXT* __restrict__ gx, const unsigned* __restrict__ whh2,
                const float* __restrict__ bih_f, const float* __restrict__ bhh_f,
                const float* __restrict__ bih_b, const float* __restrict__ bhh_b,
                const int* __restrict__ layout, float* __restrict__ out,
                unsigned* __restrict__ hx) {
  __shared__ unsigned hbufw[544];            // 2 parities x (4 quarters x 68 words)
  __shared__ int lay[Ww + 1];
  const int tid   = threadIdx.x;
  const int j     = blockIdx.x >> 6;         // shard: siblings {c, c+64, c+128, c+192}
  const int chain = blockIdx.x & 63;
  const int dir   = chain >> 5;
  const int b     = chain & 31;
  const int c     = tid >> 2;                // local hcol 0..127
  const int q     = tid & 3;                 // K-quarter
  const int col   = j * 128 + c;             // global hcol

  const uint4* wq = reinterpret_cast<const uint4*>(whh2)
                    + (size_t)(dir * 4 + j) * 48 * 512 + tid;
  H16(WDECL)
  H16(WLOAD)
  H16(WPIN)

  float bi0 = 0.f, bi1 = 0.f, bi2 = 0.f, bh0 = 0.f, bh1 = 0.f, bh2 = 0.f;
  if (q == 0) {
    const float* bi = dir ? bih_b : bih_f;
    const float* bh = dir ? bhh_b : bhh_f;
    bi0 = bi[col]; bi1 = bi[512 + col]; bi2 = bi[1024 + col];
    bh0 = bh[col]; bh1 = bh[512 + col]; bh2 = bh[1024 + col];
  }
  if (tid <= Ww) lay[tid] = layout[b * (Ww + 1) + tid];
  hbufw[tid] = 0u;
  if (tid < 32) hbufw[512 + tid] = 0u;       // h0 = 0, both parities
  __syncthreads();

  float h = 0.f, mx = -3.0e38f;
  int t = dir ? (Ss - 1) : 0;
  const int tstep = dir ? -1 : 1;
  int seg = dir ? (Ww - 1) : 0;
  int p = 0;

  // gx prefetch: current step's values live in (gr,gz,gn)
  float gr = 0.f, gz = 0.f, gn = 0.f;
  if (q == 0) {
    const GXT* gp = gx + (size_t)(t * Bb + b) * GXC + dir * 1536 + col;
    gr = gxload<GXT>(gp[0]); gz = gxload<GXT>(gp[512]); gn = gxload<GXT>(gp[1024]);
  }

  #pragma unroll 1
  for (int it = 0; it < Ss; ++it, t += tstep) {
    float ngr = 0.f, ngz = 0.f, ngn = 0.f;
    if (q == 0 && it + 1 < Ss) {             // issue NEXT step's gx now (~2us cover)
      const GXT* gp = gx + (size_t)((t + tstep) * Bb + b) * GXC + dir * 1536 + col;
      ngr = gxload<GXT>(gp[0]); ngz = gxload<GXT>(gp[512]); ngn = gxload<GXT>(gp[1024]);
    }
    float s0 = 0.f, s1 = 0.f, s2 = 0.f;
    const uint4* hq4 = reinterpret_cast<const uint4*>(hbufw) + p * 68 + q * 17;
    H16(CHUNK)
    H16(WPIN)                                // keep weights loop-carried in regs
    { float u;                               // quad butterfly over K-quarters
      u = __shfl_xor(s0, 1); s0 += u; u = __shfl_xor(s0, 2); s0 += u;
      u = __shfl_xor(s1, 1); s1 += u; u = __shfl_xor(s1, 2); s1 += u;
      u = __shfl_xor(s2, 1); s2 += u; u = __shfl_xor(s2, 2); s2 += u; }
    const int P = p ^ 1;
    if (q == 0) {
      float rs = gr + bi0 + bh0 + s0;
      float zs = gz + bi1 + bh1 + s1;
      float nh = bh2 + s2;                   // gh_n incl. b_hh_n (scaled by r)
      float r = 1.f / (1.f + __expf(-rs));
      float z = 1.f / (1.f + __expf(-zs));
      float x = gn + bi2 + r * nh;
      x = fminf(fmaxf(x, -15.f), 15.f);
      float e = __expf(2.f * x);
      float n = (e - 1.f) / (e + 1.f);       // tanh
      h = (1.f - z) * n + z * h;
      unsigned hb16 = (unsigned)__builtin_bit_cast(unsigned short, (_Float16)h);
      __hip_atomic_store(hx + ((((size_t)P * 64 + chain) * 4 + j) << 7) + c,
                         (((unsigned)(it + 1)) << 16) | hb16,
                         __ATOMIC_RELAXED, __HIP_MEMORY_SCOPE_AGENT);
      mx = fmaxf(mx, h);
      reinterpret_cast<_Float16*>(hbufw)[((P * 272 + j * 68 + (c >> 1)) << 1) | (c & 1)]
          = (_Float16)h;                     // own shard of h_{it+1} (local)
      bool flush = dir ? (t == lay[seg]) : (t + 1 == lay[seg + 1]);
      if (flush) {
        out[(size_t)(b * Ww + seg) * 1024 + dir * 512 + col] = mx;
        mx = -3.0e38f;
        seg += tstep;
      }
    }
    // (barrier A deleted: gather below touches only parity-P sibling slots,
    //  disjoint from this step's parity-p reads and own-slot writes; all
    //  parity-P writes are ordered for next step by barrier C.)
    if (it + 1 < Ss && tid < 96) {           // gather 3 sibling shards (tagged poll)
      int s = tid >> 5, qd = tid & 31;
      int sib = s + (s >= j);
      const u64* src = reinterpret_cast<const u64*>(
          hx + ((((size_t)P * 64 + chain) * 4 + sib) << 7) + (qd << 2));
      const unsigned want = (unsigned)(it + 1);
      u64 a, b2;
      for (;;) {
        a  = __hip_atomic_load(src,     __ATOMIC_RELAXED, __HIP_MEMORY_SCOPE_AGENT);
        b2 = __hip_atomic_load(src + 1, __ATOMIC_RELAXED, __HIP_MEMORY_SCOPE_AGENT);
        if (TAGOK(a, b2, want)) break;
      }
      unsigned w0 = ((unsigned)a  & 0xffffu) | (((unsigned)(a  >> 32) & 0xffffu) << 16);
      unsigned w1 = ((unsigned)b2 & 0xffffu) | (((unsigned)(b2 >> 32) & 0xffffu) << 16);
      int idx = P * 272 + sib * 68 + (qd << 1);
      hbufw[idx] = w0; hbufw[idx + 1] = w1;
    }
    __syncthreads();                         // C: full h_{it+1} in LDS
    p = P;
    gr = ngr; gz = ngz; gn = ngn;
  }
  if (q == 0)                                // final hidden [2][B][H]
    out[(size_t)Bb * Ww * 1024 + (size_t)dir * (Bb * Hh) + b * Hh + col] = h;
}

// ---------------- host launcher ----------------
extern "C" void kernel_launch(void* const* d_in, const int* in_sizes, int n_in,
                              void* d_out, int out_size, void* d_ws, size_t ws_size,
                              hipStream_t stream) {
  const int*   seq    = (const int*)  d_in[0];
  const int*   layout = (const int*)  d_in[3];
  const float* emb    = (const float*)d_in[4];
  const float* Wih_f  = (const float*)d_in[5];
  const float* Whh_f  = (const float*)d_in[6];
  const float* bih_f  = (const float*)d_in[7];
  const float* bhh_f  = (const float*)d_in[8];
  const float* Wih_b  = (const float*)d_in[9];
  const float* Whh_b  = (const float*)d_in[10];
  const float* bih_b  = (const float*)d_in[11];
  const float* bhh_b  = (const float*)d_in[12];
  float* out = (float*)d_out;

  char* ws = (char*)d_ws;
  unsigned short* embb  = (unsigned short*)ws;                      // 32,768,000 B
  unsigned short* wihb  = (unsigned short*)(ws + 32768000);         //  3,145,728 B
  unsigned*       whh2  = (unsigned*)      (ws + 35913728);         //  3,145,728 B
  unsigned*       hxw   = (unsigned*)      (ws + 39059456);         //    262,144 B
  void*           gxp   = (void*)          (ws + 39321600);

  const size_t need_f32 = 39321600ULL + (size_t)MR * GXC * 4;       // ~442.0 MB
  const size_t need_b16 = 39321600ULL + (size_t)MR * GXC * 2;       // ~240.6 MB
  if (ws_size < need_b16) return;

  prep_emb<<<(Vv * Ee) / 4 / 256, 256, 0, stream>>>(emb, embb);
  prep_wih<<<(GXC * Ee) / 4 / 256, 256, 0, stream>>>(Wih_f, Wih_b, wihb);
  prep_whh<<<(2 * 4 * 48 * 512 * 4) / 256, 256, 0, stream>>>(Whh_f, Whh_b, whh2);
  zero_hx<<<256, 256, 0, stream>>>(hxw);      // stream-ordered: runs before rnn

  if (ws_size >= need_f32) {
    gx_gemm<float><<<dim3(GXC / 128, MR / 128), 256, 0, stream>>>(seq, embb, wihb, (float*)gxp);
    rnn_kernel<float><<<256, 512, 0, stream>>>((const float*)gxp, whh2,
                                               bih_f, bhh_f, bih_b, bhh_b, layout, out, hxw);
  } else {
    gx_gemm<__hip_bfloat16><<<dim3(GXC / 128, MR / 128), 256, 0, stream>>>(seq, embb, wihb, (__hip_bfloat16*)gxp);
    rnn_kernel<__hip_bfloat16><<<256, 512, 0, stream>>>((const __hip_bfloat16*)gxp, whh2,
                                                        bih_f, bhh_f, bih_b, bhh_b, layout, out, hxw);
  }
}